// Round 1
// baseline (299.180 us; speedup 1.0000x reference)
//
#include <hip/hip_runtime.h>
#include <cstdint>

#define B_NODES 16384
#define C_CH    64
#define I_DIM   9
#define S_SPEC  10
#define K3C     23
#define K2C     5
#define K1C     2
#define NTRI    165   // unique triples p<=q<=r in [0,9)
#define NPAIR   45    // unique pairs p<=q
#define NSING   9
#define NIDX    (NTRI + NPAIR + NSING)   // 219
#define MAXTILES 266  // <= B/64 + S
#define SORT_CAP (MAXTILES * 64)
#define OUT_STRIDE (4 * C_CH)

// ---------------- sort-by-species machinery ----------------

__global__ void k_init(int* __restrict__ sorted, int* __restrict__ tilesp,
                       int* __restrict__ cnt, int* __restrict__ cursor) {
    int t = blockIdx.x * blockDim.x + threadIdx.x;
    if (t < SORT_CAP) sorted[t] = -1;
    if (t < MAXTILES) tilesp[t] = -1;
    if (t < S_SPEC) { cnt[t] = 0; cursor[t] = 0; }
}

__global__ void k_hist(const float* __restrict__ y, int* __restrict__ species,
                       int* __restrict__ cnt) {
    int b = blockIdx.x * blockDim.x + threadIdx.x;
    if (b >= B_NODES) return;
    int e = 0; float best = -1.0f;
    #pragma unroll
    for (int j = 0; j < S_SPEC; ++j) {
        float v = y[b * S_SPEC + j];
        if (v > best) { best = v; e = j; }
    }
    species[b] = e;
    atomicAdd(&cnt[e], 1);
}

__global__ void k_plan(const int* __restrict__ cnt, int* __restrict__ seg_start,
                       int* __restrict__ tilesp) {
    if (threadIdx.x != 0 || blockIdx.x != 0) return;
    int run = 0;
    for (int e = 0; e < S_SPEC; ++e) {
        seg_start[e] = run;
        int tiles = (cnt[e] + 63) >> 6;
        for (int t = 0; t < tiles; ++t) tilesp[(run >> 6) + t] = e;
        run += tiles << 6;
    }
}

__global__ void k_scatter(const int* __restrict__ species,
                          const int* __restrict__ seg_start,
                          int* __restrict__ cursor, int* __restrict__ sorted) {
    int b = blockIdx.x * blockDim.x + threadIdx.x;
    if (b >= B_NODES) return;
    int e = species[b];
    int pos = atomicAdd(&cursor[e], 1);
    sorted[seg_start[e] + pos] = b;
}

// ---------------- symmetrized table precompute ----------------
// table[((e*C + c)*NIDX + idx)*4 + m]
//   idx <  NTRI        : sum over distinct arrangements of triple (p,q,r) of A3
//   idx in [NTRI,+45)  : sum over distinct arrangements of pair (p,q) of A2
//   idx >= NTRI+NPAIR  : single A1[p]
// m=0 scalar path (U*_s, W*_s), m=1..3 vector components (U*_v[m-1], W*_v)

__global__ void k_table(const float* __restrict__ U3s, const float* __restrict__ U2s,
                        const float* __restrict__ U1s, const float* __restrict__ W3s,
                        const float* __restrict__ W2s, const float* __restrict__ W1s,
                        const float* __restrict__ U3v, const float* __restrict__ U2v,
                        const float* __restrict__ U1v, const float* __restrict__ W3v,
                        const float* __restrict__ W2v, const float* __restrict__ W1v,
                        float* __restrict__ table) {
    int tid = blockIdx.x * blockDim.x + threadIdx.x;
    if (tid >= NIDX * S_SPEC * C_CH) return;
    // lanes share idx, span (e,c) -> coalesced W loads, uniform U loads
    int idx = tid / (S_SPEC * C_CH);
    int ec  = tid % (S_SPEC * C_CH);
    int e = ec / C_CH, c = ec % C_CH;

    float acc0 = 0.f, acc1 = 0.f, acc2 = 0.f, acc3 = 0.f;

    if (idx < NTRI) {
        int p = 0, q = 0, r = 0, cum = 0;
        for (int p0 = 0; p0 < 9; ++p0)
            for (int q0 = p0; q0 < 9; ++q0)
                for (int r0 = q0; r0 < 9; ++r0) {
                    if (cum == idx) { p = p0; q = q0; r = r0; }
                    ++cum;
                }
        float w3s[K3C], w3v[K3C];
        for (int k = 0; k < K3C; ++k) {
            w3s[k] = W3s[(e * K3C + k) * C_CH + c];
            w3v[k] = W3v[(e * K3C + k) * C_CH + c];
        }
        int perm[6][3] = {{p,q,r},{p,r,q},{q,p,r},{q,r,p},{r,p,q},{r,q,p}};
        for (int j = 0; j < 6; ++j) {
            bool dup = false;
            for (int j2 = 0; j2 < j; ++j2)
                if (perm[j2][0]==perm[j][0] && perm[j2][1]==perm[j][1] && perm[j2][2]==perm[j][2])
                    dup = true;
            if (dup) continue;
            int a = perm[j][0], bb = perm[j][1], i = perm[j][2];
            int bs = ((a * 9 + bb) * 9 + i) * K3C;
            for (int k = 0; k < K3C; ++k) {
                acc0 += U3s[bs + k] * w3s[k];
                acc1 += U3v[(((0 * 9 + a) * 9 + bb) * 9 + i) * K3C + k] * w3v[k];
                acc2 += U3v[(((1 * 9 + a) * 9 + bb) * 9 + i) * K3C + k] * w3v[k];
                acc3 += U3v[(((2 * 9 + a) * 9 + bb) * 9 + i) * K3C + k] * w3v[k];
            }
        }
    } else if (idx < NTRI + NPAIR) {
        int pidx = idx - NTRI;
        int p = 0, q = 0, cum = 0;
        for (int p0 = 0; p0 < 9; ++p0)
            for (int q0 = p0; q0 < 9; ++q0) {
                if (cum == pidx) { p = p0; q = q0; }
                ++cum;
            }
        int np = (p == q) ? 1 : 2;
        int pa[2] = {p, q}, pb[2] = {q, p};
        for (int j = 0; j < np; ++j) {
            int a = pa[j], bb = pb[j];
            for (int k = 0; k < K2C; ++k) {
                float ws = W2s[(e * K2C + k) * C_CH + c];
                float wv = W2v[(e * K2C + k) * C_CH + c];
                acc0 += U2s[(a * 9 + bb) * K2C + k] * ws;
                acc1 += U2v[((0 * 9 + a) * 9 + bb) * K2C + k] * wv;
                acc2 += U2v[((1 * 9 + a) * 9 + bb) * K2C + k] * wv;
                acc3 += U2v[((2 * 9 + a) * 9 + bb) * K2C + k] * wv;
            }
        }
    } else {
        int p = idx - NTRI - NPAIR;
        for (int k = 0; k < K1C; ++k) {
            float ws = W1s[(e * K1C + k) * C_CH + c];
            float wv = W1v[(e * K1C + k) * C_CH + c];
            acc0 += U1s[p * K1C + k] * ws;
            acc1 += U1v[(0 * 9 + p) * K1C + k] * wv;
            acc2 += U1v[(1 * 9 + p) * K1C + k] * wv;
            acc3 += U1v[(2 * 9 + p) * K1C + k] * wv;
        }
    }
    float* dst = table + ((size_t)(ec * NIDX + idx)) * 4;
    dst[0] = acc0; dst[1] = acc1; dst[2] = acc2; dst[3] = acc3;
}

// ---------------- main polynomial-evaluation kernel ----------------
// 1 wave (64 threads) = 64 nodes of one species x one channel.
// Table reads are wave-uniform -> scalar loads.

__global__ __launch_bounds__(64) void k_main(const float* __restrict__ x,
                                             const float* __restrict__ table,
                                             const int* __restrict__ sorted,
                                             const int* __restrict__ tilesp,
                                             float* __restrict__ out) {
    int t = blockIdx.x;
    int c = blockIdx.y;
    int e = __builtin_amdgcn_readfirstlane(tilesp[t]);
    if (e < 0) return;
    int lane = threadIdx.x;
    int b = sorted[t * 64 + lane];

    float xr[9];
    if (b >= 0) {
        const float* xp = x + ((size_t)b * C_CH + c) * I_DIM;
        #pragma unroll
        for (int i = 0; i < 9; ++i) xr[i] = xp[i];
    } else {
        #pragma unroll
        for (int i = 0; i < 9; ++i) xr[i] = 0.f;
    }

    const float* __restrict__ T = table + (size_t)(e * C_CH + c) * (NIDX * 4);

    float a0 = 0.f, a1 = 0.f, a2 = 0.f, a3 = 0.f;
    int ti = 0, pi = 0;
    #pragma unroll
    for (int p = 0; p < 9; ++p) {
        #pragma unroll
        for (int q = p; q < 9; ++q) {
            float m2 = xr[p] * xr[q];
            a0 += T[(NTRI + pi) * 4 + 0] * m2;
            a1 += T[(NTRI + pi) * 4 + 1] * m2;
            a2 += T[(NTRI + pi) * 4 + 2] * m2;
            a3 += T[(NTRI + pi) * 4 + 3] * m2;
            ++pi;
            #pragma unroll
            for (int r = q; r < 9; ++r) {
                float m3 = m2 * xr[r];
                a0 += T[ti * 4 + 0] * m3;
                a1 += T[ti * 4 + 1] * m3;
                a2 += T[ti * 4 + 2] * m3;
                a3 += T[ti * 4 + 3] * m3;
                ++ti;
            }
        }
        // singles
        a0 += T[(NTRI + NPAIR + p) * 4 + 0] * xr[p];
        a1 += T[(NTRI + NPAIR + p) * 4 + 1] * xr[p];
        a2 += T[(NTRI + NPAIR + p) * 4 + 2] * xr[p];
        a3 += T[(NTRI + NPAIR + p) * 4 + 3] * xr[p];
    }

    if (b >= 0) {
        float* o = out + (size_t)b * OUT_STRIDE;
        o[c] = a0;
        o[C_CH + c * 3 + 0] = a1;
        o[C_CH + c * 3 + 1] = a2;
        o[C_CH + c * 3 + 2] = a3;
    }
}

// ---------------- launcher ----------------

extern "C" void kernel_launch(void* const* d_in, const int* in_sizes, int n_in,
                              void* d_out, int out_size, void* d_ws, size_t ws_size,
                              hipStream_t stream) {
    const float* x   = (const float*)d_in[0];
    const float* y   = (const float*)d_in[1];
    const float* U3s = (const float*)d_in[2];
    const float* U2s = (const float*)d_in[3];
    const float* U1s = (const float*)d_in[4];
    const float* W3s = (const float*)d_in[5];
    const float* W2s = (const float*)d_in[6];
    const float* W1s = (const float*)d_in[7];
    const float* U3v = (const float*)d_in[8];
    const float* U2v = (const float*)d_in[9];
    const float* U1v = (const float*)d_in[10];
    const float* W3v = (const float*)d_in[11];
    const float* W2v = (const float*)d_in[12];
    const float* W1v = (const float*)d_in[13];
    float* out = (float*)d_out;

    char* ws = (char*)d_ws;
    size_t off = 0;
    auto alloc = [&](size_t bytes) -> char* {
        char* p = ws + off;
        off = (off + bytes + 255) & ~(size_t)255;
        return p;
    };
    float* table   = (float*)alloc((size_t)S_SPEC * C_CH * NIDX * 4 * sizeof(float));
    int* sorted    = (int*)alloc(SORT_CAP * sizeof(int));
    int* tilesp    = (int*)alloc(MAXTILES * sizeof(int));
    int* species   = (int*)alloc(B_NODES * sizeof(int));
    int* cnt       = (int*)alloc(S_SPEC * sizeof(int));
    int* cursor    = (int*)alloc(S_SPEC * sizeof(int));
    int* seg_start = (int*)alloc(S_SPEC * sizeof(int));

    hipLaunchKernelGGL(k_init, dim3((SORT_CAP + 255) / 256), dim3(256), 0, stream,
                       sorted, tilesp, cnt, cursor);
    hipLaunchKernelGGL(k_hist, dim3((B_NODES + 255) / 256), dim3(256), 0, stream,
                       y, species, cnt);
    hipLaunchKernelGGL(k_plan, dim3(1), dim3(1), 0, stream, cnt, seg_start, tilesp);
    hipLaunchKernelGGL(k_scatter, dim3((B_NODES + 255) / 256), dim3(256), 0, stream,
                       species, seg_start, cursor, sorted);

    int table_threads = NIDX * S_SPEC * C_CH;
    hipLaunchKernelGGL(k_table, dim3((table_threads + 255) / 256), dim3(256), 0, stream,
                       U3s, U2s, U1s, W3s, W2s, W1s, U3v, U2v, U1v, W3v, W2v, W1v, table);

    hipLaunchKernelGGL(k_main, dim3(MAXTILES, C_CH), dim3(64), 0, stream,
                       x, table, sorted, tilesp, out);
}

// Round 2
// 165.297 us; speedup vs baseline: 1.8100x; 1.8100x over previous
//
#include <hip/hip_runtime.h>
#include <cstdint>

#define B_NODES 16384
#define C_CH    64
#define I_DIM   9
#define S_SPEC  10
#define K3C     23
#define K2C     5
#define K1C     2
#define NTRI    165   // unique triples p<=q<=r in [0,9)
#define NPAIR   45    // unique pairs p<=q
#define NSING   9
#define NIDX    (NTRI + NPAIR + NSING)   // 219
#define MAXTILES 266  // <= B/64 + S
#define SORT_CAP (MAXTILES * 64)
#define OUT_STRIDE (4 * C_CH)
#define G_CH 8        // channels per block

typedef float v2f __attribute__((ext_vector_type(2)));

// ---------------- sort-by-species machinery ----------------

__global__ void k_init(int* __restrict__ sorted, int* __restrict__ tilesp,
                       int* __restrict__ cnt, int* __restrict__ cursor) {
    int t = blockIdx.x * blockDim.x + threadIdx.x;
    if (t < SORT_CAP) sorted[t] = -1;
    if (t < MAXTILES) tilesp[t] = -1;
    if (t < S_SPEC) { cnt[t] = 0; cursor[t] = 0; }
}

__global__ void k_hist(const float* __restrict__ y, int* __restrict__ species,
                       int* __restrict__ cnt) {
    int b = blockIdx.x * blockDim.x + threadIdx.x;
    if (b >= B_NODES) return;
    int e = 0; float best = -1.0f;
    #pragma unroll
    for (int j = 0; j < S_SPEC; ++j) {
        float v = y[b * S_SPEC + j];
        if (v > best) { best = v; e = j; }
    }
    species[b] = e;
    int lane = threadIdx.x & 63;
    // wave-aggregated histogram: 1 atomic per (wave, species)
    for (int j = 0; j < S_SPEC; ++j) {
        unsigned long long m = __ballot(e == j);
        if (m != 0ull) {
            int leader = __ffsll((unsigned long long)m) - 1;
            if (lane == leader) atomicAdd(&cnt[j], __popcll(m));
        }
    }
}

__global__ void k_plan(const int* __restrict__ cnt, int* __restrict__ seg_start,
                       int* __restrict__ tilesp) {
    if (threadIdx.x != 0 || blockIdx.x != 0) return;
    int run = 0;
    for (int e = 0; e < S_SPEC; ++e) {
        seg_start[e] = run;
        int tiles = (cnt[e] + 63) >> 6;
        for (int t = 0; t < tiles; ++t) tilesp[(run >> 6) + t] = e;
        run += tiles << 6;
    }
}

__global__ void k_scatter(const int* __restrict__ species,
                          const int* __restrict__ seg_start,
                          int* __restrict__ cursor, int* __restrict__ sorted) {
    int b = blockIdx.x * blockDim.x + threadIdx.x;
    if (b >= B_NODES) return;
    int e = species[b];
    int lane = threadIdx.x & 63;
    unsigned long long lanebit = 1ull << lane;
    for (int j = 0; j < S_SPEC; ++j) {
        unsigned long long m = __ballot(e == j);
        if (m == 0ull) continue;                    // wave-uniform
        int leader = __ffsll((unsigned long long)m) - 1;
        int base = 0;
        if (lane == leader) base = atomicAdd(&cursor[j], __popcll(m));
        base = __shfl(base, leader);
        if (e == j) {
            int pos = base + __popcll(m & (lanebit - 1ull));
            sorted[seg_start[j] + pos] = b;
        }
    }
}

// ---------------- symmetrized table precompute ----------------
// table[((e*C + c)*NIDX + idx)*4 + m]

__global__ void k_table(const float* __restrict__ U3s, const float* __restrict__ U2s,
                        const float* __restrict__ U1s, const float* __restrict__ W3s,
                        const float* __restrict__ W2s, const float* __restrict__ W1s,
                        const float* __restrict__ U3v, const float* __restrict__ U2v,
                        const float* __restrict__ U1v, const float* __restrict__ W3v,
                        const float* __restrict__ W2v, const float* __restrict__ W1v,
                        float* __restrict__ table) {
    int tid = blockIdx.x * blockDim.x + threadIdx.x;
    if (tid >= NIDX * S_SPEC * C_CH) return;
    int idx = tid / (S_SPEC * C_CH);
    int ec  = tid % (S_SPEC * C_CH);
    int e = ec / C_CH, c = ec % C_CH;

    float acc0 = 0.f, acc1 = 0.f, acc2 = 0.f, acc3 = 0.f;

    if (idx < NTRI) {
        int p = 0, q = 0, r = 0, cum = 0;
        for (int p0 = 0; p0 < 9; ++p0)
            for (int q0 = p0; q0 < 9; ++q0)
                for (int r0 = q0; r0 < 9; ++r0) {
                    if (cum == idx) { p = p0; q = q0; r = r0; }
                    ++cum;
                }
        float w3s[K3C], w3v[K3C];
        for (int k = 0; k < K3C; ++k) {
            w3s[k] = W3s[(e * K3C + k) * C_CH + c];
            w3v[k] = W3v[(e * K3C + k) * C_CH + c];
        }
        int perm[6][3] = {{p,q,r},{p,r,q},{q,p,r},{q,r,p},{r,p,q},{r,q,p}};
        for (int j = 0; j < 6; ++j) {
            bool dup = false;
            for (int j2 = 0; j2 < j; ++j2)
                if (perm[j2][0]==perm[j][0] && perm[j2][1]==perm[j][1] && perm[j2][2]==perm[j][2])
                    dup = true;
            if (dup) continue;
            int a = perm[j][0], bb = perm[j][1], i = perm[j][2];
            int bs = ((a * 9 + bb) * 9 + i) * K3C;
            for (int k = 0; k < K3C; ++k) {
                acc0 += U3s[bs + k] * w3s[k];
                acc1 += U3v[(((0 * 9 + a) * 9 + bb) * 9 + i) * K3C + k] * w3v[k];
                acc2 += U3v[(((1 * 9 + a) * 9 + bb) * 9 + i) * K3C + k] * w3v[k];
                acc3 += U3v[(((2 * 9 + a) * 9 + bb) * 9 + i) * K3C + k] * w3v[k];
            }
        }
    } else if (idx < NTRI + NPAIR) {
        int pidx = idx - NTRI;
        int p = 0, q = 0, cum = 0;
        for (int p0 = 0; p0 < 9; ++p0)
            for (int q0 = p0; q0 < 9; ++q0) {
                if (cum == pidx) { p = p0; q = q0; }
                ++cum;
            }
        int np = (p == q) ? 1 : 2;
        int pa[2] = {p, q}, pb[2] = {q, p};
        for (int j = 0; j < np; ++j) {
            int a = pa[j], bb = pb[j];
            for (int k = 0; k < K2C; ++k) {
                float ws = W2s[(e * K2C + k) * C_CH + c];
                float wv = W2v[(e * K2C + k) * C_CH + c];
                acc0 += U2s[(a * 9 + bb) * K2C + k] * ws;
                acc1 += U2v[((0 * 9 + a) * 9 + bb) * K2C + k] * wv;
                acc2 += U2v[((1 * 9 + a) * 9 + bb) * K2C + k] * wv;
                acc3 += U2v[((2 * 9 + a) * 9 + bb) * K2C + k] * wv;
            }
        }
    } else {
        int p = idx - NTRI - NPAIR;
        for (int k = 0; k < K1C; ++k) {
            float ws = W1s[(e * K1C + k) * C_CH + c];
            float wv = W1v[(e * K1C + k) * C_CH + c];
            acc0 += U1s[p * K1C + k] * ws;
            acc1 += U1v[(0 * 9 + p) * K1C + k] * wv;
            acc2 += U1v[(1 * 9 + p) * K1C + k] * wv;
            acc3 += U1v[(2 * 9 + p) * K1C + k] * wv;
        }
    }
    float* dst = table + ((size_t)(ec * NIDX + idx)) * 4;
    dst[0] = acc0; dst[1] = acc1; dst[2] = acc2; dst[3] = acc3;
}

// ---------------- main polynomial-evaluation kernel ----------------
// Block = 256 thr = 4 waves. Tile t (64 nodes, same species) x channel-group g
// (8 channels). x staged coalesced into LDS (stride 73: conflict-free reads),
// outputs staged in LDS (stride 33) then written as aligned float4 segments.
// Table reads wave-uniform -> s_load stream. float2 accs -> v_pk_fma_f32.

__global__ __launch_bounds__(256) void k_main(const float* __restrict__ x,
                                              const float* __restrict__ table,
                                              const int* __restrict__ sorted,
                                              const int* __restrict__ tilesp,
                                              float* __restrict__ out) {
    __shared__ float xs[64 * 73];   // 64 nodes x (8ch*9 = 72, pad->73)
    __shared__ float os[64 * 33];   // 64 nodes x (8 scal + 24 vec, pad->33)
    __shared__ int   bs[64];

    int t = blockIdx.x, g = blockIdx.y;
    int e = __builtin_amdgcn_readfirstlane(tilesp[t]);
    if (e < 0) return;
    int tid = threadIdx.x;
    if (tid < 64) bs[tid] = sorted[t * 64 + tid];
    __syncthreads();

    // ---- load phase: per node 288B contiguous (8ch x 9 floats) ----
    for (int s = tid; s < 64 * 18; s += 256) {
        int n = s / 18, j = s % 18;
        int b = bs[n];
        float4 v = make_float4(0.f, 0.f, 0.f, 0.f);
        if (b >= 0)
            v = *(const float4*)(x + (size_t)b * (C_CH * I_DIM) + g * (G_CH * I_DIM) + j * 4);
        float* d = &xs[n * 73 + j * 4];
        d[0] = v.x; d[1] = v.y; d[2] = v.z; d[3] = v.w;
    }
    __syncthreads();

    int w = __builtin_amdgcn_readfirstlane(tid >> 6);
    int l = tid & 63;

    for (int cc = 0; cc < 2; ++cc) {
        int ci = w * 2 + cc;          // channel within group
        int c  = g * G_CH + ci;       // global channel
        const float* __restrict__ T =
            table + (size_t)__builtin_amdgcn_readfirstlane((e * C_CH + c) * (NIDX * 4));

        float xr[9];
        #pragma unroll
        for (int i = 0; i < 9; ++i) xr[i] = xs[l * 73 + ci * 9 + i];

        v2f acc01 = {0.f, 0.f}, acc23 = {0.f, 0.f};
        int ti = 0, pi = 0;
        #pragma unroll
        for (int p = 0; p < 9; ++p) {
            #pragma unroll
            for (int q = p; q < 9; ++q) {
                float m2 = xr[p] * xr[q];
                const float* Tp = T + (NTRI + pi) * 4;
                acc01 += (*(const v2f*)(Tp)) * m2;
                acc23 += (*(const v2f*)(Tp + 2)) * m2;
                ++pi;
                #pragma unroll
                for (int r = q; r < 9; ++r) {
                    float m3 = m2 * xr[r];
                    const float* Tt = T + ti * 4;
                    acc01 += (*(const v2f*)(Tt)) * m3;
                    acc23 += (*(const v2f*)(Tt + 2)) * m3;
                    ++ti;
                }
            }
            const float* Ts = T + (NTRI + NPAIR + p) * 4;
            acc01 += (*(const v2f*)(Ts)) * xr[p];
            acc23 += (*(const v2f*)(Ts + 2)) * xr[p];
        }

        os[l * 33 + ci]               = acc01.x;
        os[l * 33 + 8 + ci * 3 + 0]   = acc01.y;
        os[l * 33 + 8 + ci * 3 + 1]   = acc23.x;
        os[l * 33 + 8 + ci * 3 + 2]   = acc23.y;
    }
    __syncthreads();

    // ---- write phase: per node 32B scalar seg + 96B vector seg, f4-aligned ----
    for (int s = tid; s < 64 * 8; s += 256) {
        int n = s >> 3, j = s & 7;
        int b = bs[n];
        if (b < 0) continue;
        const float* src;
        float* dst;
        if (j < 2) {
            src = &os[n * 33 + j * 4];
            dst = out + (size_t)b * OUT_STRIDE + g * G_CH + j * 4;
        } else {
            int vj = j - 2;
            src = &os[n * 33 + 8 + vj * 4];
            dst = out + (size_t)b * OUT_STRIDE + C_CH + g * (3 * G_CH) + vj * 4;
        }
        float4 v;
        v.x = src[0]; v.y = src[1]; v.z = src[2]; v.w = src[3];
        *(float4*)dst = v;
    }
}

// ---------------- launcher ----------------

extern "C" void kernel_launch(void* const* d_in, const int* in_sizes, int n_in,
                              void* d_out, int out_size, void* d_ws, size_t ws_size,
                              hipStream_t stream) {
    const float* x   = (const float*)d_in[0];
    const float* y   = (const float*)d_in[1];
    const float* U3s = (const float*)d_in[2];
    const float* U2s = (const float*)d_in[3];
    const float* U1s = (const float*)d_in[4];
    const float* W3s = (const float*)d_in[5];
    const float* W2s = (const float*)d_in[6];
    const float* W1s = (const float*)d_in[7];
    const float* U3v = (const float*)d_in[8];
    const float* U2v = (const float*)d_in[9];
    const float* U1v = (const float*)d_in[10];
    const float* W3v = (const float*)d_in[11];
    const float* W2v = (const float*)d_in[12];
    const float* W1v = (const float*)d_in[13];
    float* out = (float*)d_out;

    char* ws = (char*)d_ws;
    size_t off = 0;
    auto alloc = [&](size_t bytes) -> char* {
        char* p = ws + off;
        off = (off + bytes + 255) & ~(size_t)255;
        return p;
    };
    float* table   = (float*)alloc((size_t)S_SPEC * C_CH * NIDX * 4 * sizeof(float));
    int* sorted    = (int*)alloc(SORT_CAP * sizeof(int));
    int* tilesp    = (int*)alloc(MAXTILES * sizeof(int));
    int* species   = (int*)alloc(B_NODES * sizeof(int));
    int* cnt       = (int*)alloc(S_SPEC * sizeof(int));
    int* cursor    = (int*)alloc(S_SPEC * sizeof(int));
    int* seg_start = (int*)alloc(S_SPEC * sizeof(int));

    hipLaunchKernelGGL(k_init, dim3((SORT_CAP + 255) / 256), dim3(256), 0, stream,
                       sorted, tilesp, cnt, cursor);
    hipLaunchKernelGGL(k_hist, dim3(B_NODES / 256), dim3(256), 0, stream,
                       y, species, cnt);
    hipLaunchKernelGGL(k_plan, dim3(1), dim3(1), 0, stream, cnt, seg_start, tilesp);
    hipLaunchKernelGGL(k_scatter, dim3(B_NODES / 256), dim3(256), 0, stream,
                       species, seg_start, cursor, sorted);

    int table_threads = NIDX * S_SPEC * C_CH;
    hipLaunchKernelGGL(k_table, dim3((table_threads + 255) / 256), dim3(256), 0, stream,
                       U3s, U2s, U1s, W3s, W2s, W1s, U3v, U2v, U1v, W3v, W2v, W1v, table);

    hipLaunchKernelGGL(k_main, dim3(MAXTILES, G_CH), dim3(64 * 4), 0, stream,
                       x, table, sorted, tilesp, out);
}

// Round 3
// 144.752 us; speedup vs baseline: 2.0668x; 1.1419x over previous
//
#include <hip/hip_runtime.h>
#include <cstdint>

#define B_NODES 16384
#define C_CH    64
#define I_DIM   9
#define S_SPEC  10
#define K3C     23
#define K2C     5
#define K1C     2
#define NTRI    165   // unique triples p<=q<=r in [0,9)
#define NPAIR   45    // unique pairs p<=q
#define NSING   9
#define NIDX    (NTRI + NPAIR + NSING)   // 219
#define MAXTILES 266  // <= B/64 + S
#define SORT_CAP (MAXTILES * 64)
#define OUT_STRIDE (4 * C_CH)
#define G_CH 8        // channels per block

#define N3SL (NTRI * K3C)    // 3795
#define N2SL (NPAIR * K2C)   // 225
#define N1SL (NSING * K1C)   // 18

typedef float v2f __attribute__((ext_vector_type(2)));

// ---------------- sort-by-species machinery ----------------

__global__ void k_init(int* __restrict__ sorted, int* __restrict__ tilesp,
                       int* __restrict__ cnt, int* __restrict__ cursor) {
    int t = blockIdx.x * blockDim.x + threadIdx.x;
    if (t < SORT_CAP) sorted[t] = -1;
    if (t < MAXTILES) tilesp[t] = -1;
    if (t < S_SPEC) { cnt[t] = 0; cursor[t] = 0; }
}

__global__ void k_hist(const float* __restrict__ y, int* __restrict__ species,
                       int* __restrict__ cnt) {
    int b = blockIdx.x * blockDim.x + threadIdx.x;
    if (b >= B_NODES) return;
    int e = 0; float best = -1.0f;
    #pragma unroll
    for (int j = 0; j < S_SPEC; ++j) {
        float v = y[b * S_SPEC + j];
        if (v > best) { best = v; e = j; }
    }
    species[b] = e;
    int lane = threadIdx.x & 63;
    for (int j = 0; j < S_SPEC; ++j) {
        unsigned long long m = __ballot(e == j);
        if (m != 0ull) {
            int leader = __ffsll((unsigned long long)m) - 1;
            if (lane == leader) atomicAdd(&cnt[j], __popcll(m));
        }
    }
}

__global__ void k_plan(const int* __restrict__ cnt, int* __restrict__ seg_start,
                       int* __restrict__ tilesp) {
    if (threadIdx.x != 0 || blockIdx.x != 0) return;
    int run = 0;
    for (int e = 0; e < S_SPEC; ++e) {
        seg_start[e] = run;
        int tiles = (cnt[e] + 63) >> 6;
        for (int t = 0; t < tiles; ++t) tilesp[(run >> 6) + t] = e;
        run += tiles << 6;
    }
}

__global__ void k_scatter(const int* __restrict__ species,
                          const int* __restrict__ seg_start,
                          int* __restrict__ cursor, int* __restrict__ sorted) {
    int b = blockIdx.x * blockDim.x + threadIdx.x;
    if (b >= B_NODES) return;
    int e = species[b];
    int lane = threadIdx.x & 63;
    unsigned long long lanebit = 1ull << lane;
    for (int j = 0; j < S_SPEC; ++j) {
        unsigned long long m = __ballot(e == j);
        if (m == 0ull) continue;
        int leader = __ffsll((unsigned long long)m) - 1;
        int base = 0;
        if (lane == leader) base = atomicAdd(&cursor[j], __popcll(m));
        base = __shfl(base, leader);
        if (e == j) {
            int pos = base + __popcll(m & (lanebit - 1ull));
            sorted[seg_start[j] + pos] = b;
        }
    }
}

// ---------------- stage 1: symmetrize U over distinct permutations ----------------
// us3[idx*K3C+k], uv3[m*N3SL + idx*K3C+k], similarly order 2 / 1.

__global__ void k_usym(const float* __restrict__ U3s, const float* __restrict__ U2s,
                       const float* __restrict__ U1s,
                       const float* __restrict__ U3v, const float* __restrict__ U2v,
                       const float* __restrict__ U1v,
                       float* __restrict__ us3, float* __restrict__ uv3,
                       float* __restrict__ us2, float* __restrict__ uv2,
                       float* __restrict__ us1, float* __restrict__ uv1) {
    int tid = blockIdx.x * blockDim.x + threadIdx.x;
    if (tid >= N3SL + N2SL + N1SL) return;

    if (tid < N3SL) {
        int idx = tid / K3C, k = tid % K3C;
        int p = 0, q = 0, r = 0, cum = 0;
        for (int p0 = 0; p0 < 9; ++p0)
            for (int q0 = p0; q0 < 9; ++q0)
                for (int r0 = q0; r0 < 9; ++r0) {
                    if (cum == idx) { p = p0; q = q0; r = r0; }
                    ++cum;
                }
        int perm[6][3] = {{p,q,r},{p,r,q},{q,p,r},{q,r,p},{r,p,q},{r,q,p}};
        float a0 = 0.f, a1 = 0.f, a2 = 0.f, a3 = 0.f;
        for (int j = 0; j < 6; ++j) {
            bool dup = false;
            for (int j2 = 0; j2 < j; ++j2)
                if (perm[j2][0]==perm[j][0] && perm[j2][1]==perm[j][1] && perm[j2][2]==perm[j][2])
                    dup = true;
            if (dup) continue;
            int a = perm[j][0], bb = perm[j][1], i = perm[j][2];
            int off = ((a * 9 + bb) * 9 + i) * K3C + k;
            a0 += U3s[off];
            a1 += U3v[0 * 729 * K3C + off];
            a2 += U3v[1 * 729 * K3C + off];
            a3 += U3v[2 * 729 * K3C + off];
        }
        us3[tid] = a0;
        uv3[0 * N3SL + tid] = a1;
        uv3[1 * N3SL + tid] = a2;
        uv3[2 * N3SL + tid] = a3;
    } else if (tid < N3SL + N2SL) {
        int t2 = tid - N3SL;
        int idx = t2 / K2C, k = t2 % K2C;
        int p = 0, q = 0, cum = 0;
        for (int p0 = 0; p0 < 9; ++p0)
            for (int q0 = p0; q0 < 9; ++q0) {
                if (cum == idx) { p = p0; q = q0; }
                ++cum;
            }
        int np = (p == q) ? 1 : 2;
        int pa[2] = {p, q}, pb[2] = {q, p};
        float a0 = 0.f, a1 = 0.f, a2 = 0.f, a3 = 0.f;
        for (int j = 0; j < np; ++j) {
            int off = (pa[j] * 9 + pb[j]) * K2C + k;
            a0 += U2s[off];
            a1 += U2v[0 * 81 * K2C + off];
            a2 += U2v[1 * 81 * K2C + off];
            a3 += U2v[2 * 81 * K2C + off];
        }
        us2[t2] = a0;
        uv2[0 * N2SL + t2] = a1;
        uv2[1 * N2SL + t2] = a2;
        uv2[2 * N2SL + t2] = a3;
    } else {
        int t1 = tid - N3SL - N2SL;   // p*K1C + k
        int p = t1 / K1C, k = t1 % K1C;
        int off = p * K1C + k;
        us1[t1] = U1s[off];
        uv1[0 * N1SL + t1] = U1v[0 * 9 * K1C + off];
        uv1[1 * N1SL + t1] = U1v[1 * 9 * K1C + off];
        uv1[2 * N1SL + t1] = U1v[2 * 9 * K1C + off];
    }
}

// ---------------- stage 2: table[(ec*NIDX+idx)*4+m] = sum_k Usym * W ----------------
// tid = idx*640 + ec; wave-uniform idx & e, coalesced c.

__global__ void k_table(const float* __restrict__ W3s, const float* __restrict__ W2s,
                        const float* __restrict__ W1s,
                        const float* __restrict__ W3v, const float* __restrict__ W2v,
                        const float* __restrict__ W1v,
                        const float* __restrict__ us3, const float* __restrict__ uv3,
                        const float* __restrict__ us2, const float* __restrict__ uv2,
                        const float* __restrict__ us1, const float* __restrict__ uv1,
                        float* __restrict__ table) {
    int tid = blockIdx.x * blockDim.x + threadIdx.x;
    if (tid >= NIDX * S_SPEC * C_CH) return;
    int idx = __builtin_amdgcn_readfirstlane(tid / (S_SPEC * C_CH));
    int ec  = tid % (S_SPEC * C_CH);
    int e   = __builtin_amdgcn_readfirstlane(ec / C_CH);
    int c   = ec % C_CH;

    float a0 = 0.f, a1 = 0.f, a2 = 0.f, a3 = 0.f;

    if (idx < NTRI) {
        const float* u = us3 + idx * K3C;
        #pragma unroll
        for (int k = 0; k < K3C; ++k) {
            float ws = W3s[(e * K3C + k) * C_CH + c];
            float wv = W3v[(e * K3C + k) * C_CH + c];
            a0 += u[k] * ws;
            a1 += uv3[0 * N3SL + idx * K3C + k] * wv;
            a2 += uv3[1 * N3SL + idx * K3C + k] * wv;
            a3 += uv3[2 * N3SL + idx * K3C + k] * wv;
        }
    } else if (idx < NTRI + NPAIR) {
        int i2 = idx - NTRI;
        #pragma unroll
        for (int k = 0; k < K2C; ++k) {
            float ws = W2s[(e * K2C + k) * C_CH + c];
            float wv = W2v[(e * K2C + k) * C_CH + c];
            a0 += us2[i2 * K2C + k] * ws;
            a1 += uv2[0 * N2SL + i2 * K2C + k] * wv;
            a2 += uv2[1 * N2SL + i2 * K2C + k] * wv;
            a3 += uv2[2 * N2SL + i2 * K2C + k] * wv;
        }
    } else {
        int i1 = idx - NTRI - NPAIR;
        #pragma unroll
        for (int k = 0; k < K1C; ++k) {
            float ws = W1s[(e * K1C + k) * C_CH + c];
            float wv = W1v[(e * K1C + k) * C_CH + c];
            a0 += us1[i1 * K1C + k] * ws;
            a1 += uv1[0 * N1SL + i1 * K1C + k] * wv;
            a2 += uv1[1 * N1SL + i1 * K1C + k] * wv;
            a3 += uv1[2 * N1SL + i1 * K1C + k] * wv;
        }
    }
    float* dst = table + ((size_t)(ec * NIDX + idx)) * 4;
    dst[0] = a0; dst[1] = a1; dst[2] = a2; dst[3] = a3;
}

// ---------------- main polynomial-evaluation kernel ----------------
// Block = 256 thr = 4 waves: tile t (64 same-species nodes) x 8 channels.
// LDS: xs and os UNION'd (xr pulled to registers first) -> ~19KB -> 8 blocks/CU.

__global__ __launch_bounds__(256) void k_main(const float* __restrict__ x,
                                              const float* __restrict__ table,
                                              const int* __restrict__ sorted,
                                              const int* __restrict__ tilesp,
                                              float* __restrict__ out) {
    __shared__ float smem[64 * 73];   // xs: 64 nodes x 72 (pad 73); reused as os: 64 x 33
    __shared__ int   bs[64];

    int t = blockIdx.x, g = blockIdx.y;
    int e = __builtin_amdgcn_readfirstlane(tilesp[t]);
    if (e < 0) return;
    int tid = threadIdx.x;
    if (tid < 64) bs[tid] = sorted[t * 64 + tid];
    __syncthreads();

    // ---- load phase: per node 288B contiguous (8ch x 9 floats) ----
    for (int s = tid; s < 64 * 18; s += 256) {
        int n = s / 18, j = s % 18;
        int b = bs[n];
        float4 v = make_float4(0.f, 0.f, 0.f, 0.f);
        if (b >= 0)
            v = *(const float4*)(x + (size_t)b * (C_CH * I_DIM) + g * (G_CH * I_DIM) + j * 4);
        float* d = &smem[n * 73 + j * 4];
        d[0] = v.x; d[1] = v.y; d[2] = v.z; d[3] = v.w;
    }
    __syncthreads();

    int w = __builtin_amdgcn_readfirstlane(tid >> 6);
    int l = tid & 63;

    // pull both channels' x into registers so LDS can be reused for outputs
    float xr2[2][9];
    #pragma unroll
    for (int cc = 0; cc < 2; ++cc) {
        int ci = w * 2 + cc;
        #pragma unroll
        for (int i = 0; i < 9; ++i) xr2[cc][i] = smem[l * 73 + ci * 9 + i];
    }
    __syncthreads();   // all xs reads done; smem becomes os

    #pragma unroll
    for (int cc = 0; cc < 2; ++cc) {
        int ci = w * 2 + cc;
        int c  = g * G_CH + ci;
        const float* __restrict__ T =
            table + (size_t)__builtin_amdgcn_readfirstlane((e * C_CH + c) * (NIDX * 4));

        v2f acc01 = {0.f, 0.f}, acc23 = {0.f, 0.f};
        int ti = 0, pi = 0;
        #pragma unroll
        for (int p = 0; p < 9; ++p) {
            #pragma unroll
            for (int q = p; q < 9; ++q) {
                float m2 = xr2[cc][p] * xr2[cc][q];
                const float* Tp = T + (NTRI + pi) * 4;
                acc01 += (*(const v2f*)(Tp)) * m2;
                acc23 += (*(const v2f*)(Tp + 2)) * m2;
                ++pi;
                #pragma unroll
                for (int r = q; r < 9; ++r) {
                    float m3 = m2 * xr2[cc][r];
                    const float* Tt = T + ti * 4;
                    acc01 += (*(const v2f*)(Tt)) * m3;
                    acc23 += (*(const v2f*)(Tt + 2)) * m3;
                    ++ti;
                }
            }
            const float* Ts = T + (NTRI + NPAIR + p) * 4;
            acc01 += (*(const v2f*)(Ts)) * xr2[cc][p];
            acc23 += (*(const v2f*)(Ts + 2)) * xr2[cc][p];
        }

        smem[l * 33 + ci]             = acc01.x;
        smem[l * 33 + 8 + ci * 3 + 0] = acc01.y;
        smem[l * 33 + 8 + ci * 3 + 1] = acc23.x;
        smem[l * 33 + 8 + ci * 3 + 2] = acc23.y;
    }
    __syncthreads();

    // ---- write phase: per node 32B scalar seg + 96B vector seg, f4-aligned ----
    for (int s = tid; s < 64 * 8; s += 256) {
        int n = s >> 3, j = s & 7;
        int b = bs[n];
        if (b < 0) continue;
        const float* src;
        float* dst;
        if (j < 2) {
            src = &smem[n * 33 + j * 4];
            dst = out + (size_t)b * OUT_STRIDE + g * G_CH + j * 4;
        } else {
            int vj = j - 2;
            src = &smem[n * 33 + 8 + vj * 4];
            dst = out + (size_t)b * OUT_STRIDE + C_CH + g * (3 * G_CH) + vj * 4;
        }
        float4 v;
        v.x = src[0]; v.y = src[1]; v.z = src[2]; v.w = src[3];
        *(float4*)dst = v;
    }
}

// ---------------- launcher ----------------

extern "C" void kernel_launch(void* const* d_in, const int* in_sizes, int n_in,
                              void* d_out, int out_size, void* d_ws, size_t ws_size,
                              hipStream_t stream) {
    const float* x   = (const float*)d_in[0];
    const float* y   = (const float*)d_in[1];
    const float* U3s = (const float*)d_in[2];
    const float* U2s = (const float*)d_in[3];
    const float* U1s = (const float*)d_in[4];
    const float* W3s = (const float*)d_in[5];
    const float* W2s = (const float*)d_in[6];
    const float* W1s = (const float*)d_in[7];
    const float* U3v = (const float*)d_in[8];
    const float* U2v = (const float*)d_in[9];
    const float* U1v = (const float*)d_in[10];
    const float* W3v = (const float*)d_in[11];
    const float* W2v = (const float*)d_in[12];
    const float* W1v = (const float*)d_in[13];
    float* out = (float*)d_out;

    char* ws = (char*)d_ws;
    size_t off = 0;
    auto alloc = [&](size_t bytes) -> char* {
        char* p = ws + off;
        off = (off + bytes + 255) & ~(size_t)255;
        return p;
    };
    float* table   = (float*)alloc((size_t)S_SPEC * C_CH * NIDX * 4 * sizeof(float));
    float* us3     = (float*)alloc(N3SL * sizeof(float));
    float* uv3     = (float*)alloc(3 * N3SL * sizeof(float));
    float* us2     = (float*)alloc(N2SL * sizeof(float));
    float* uv2     = (float*)alloc(3 * N2SL * sizeof(float));
    float* us1     = (float*)alloc(N1SL * sizeof(float));
    float* uv1     = (float*)alloc(3 * N1SL * sizeof(float));
    int* sorted    = (int*)alloc(SORT_CAP * sizeof(int));
    int* tilesp    = (int*)alloc(MAXTILES * sizeof(int));
    int* species   = (int*)alloc(B_NODES * sizeof(int));
    int* cnt       = (int*)alloc(S_SPEC * sizeof(int));
    int* cursor    = (int*)alloc(S_SPEC * sizeof(int));
    int* seg_start = (int*)alloc(S_SPEC * sizeof(int));

    hipLaunchKernelGGL(k_init, dim3((SORT_CAP + 255) / 256), dim3(256), 0, stream,
                       sorted, tilesp, cnt, cursor);
    hipLaunchKernelGGL(k_hist, dim3(B_NODES / 256), dim3(256), 0, stream,
                       y, species, cnt);
    hipLaunchKernelGGL(k_plan, dim3(1), dim3(1), 0, stream, cnt, seg_start, tilesp);
    hipLaunchKernelGGL(k_scatter, dim3(B_NODES / 256), dim3(256), 0, stream,
                       species, seg_start, cursor, sorted);

    int usym_threads = N3SL + N2SL + N1SL;
    hipLaunchKernelGGL(k_usym, dim3((usym_threads + 255) / 256), dim3(256), 0, stream,
                       U3s, U2s, U1s, U3v, U2v, U1v,
                       us3, uv3, us2, uv2, us1, uv1);

    int table_threads = NIDX * S_SPEC * C_CH;
    hipLaunchKernelGGL(k_table, dim3((table_threads + 255) / 256), dim3(256), 0, stream,
                       W3s, W2s, W1s, W3v, W2v, W1v,
                       us3, uv3, us2, uv2, us1, uv1, table);

    hipLaunchKernelGGL(k_main, dim3(MAXTILES, G_CH), dim3(64 * 4), 0, stream,
                       x, table, sorted, tilesp, out);
}